// Round 2
// baseline (109.573 us; speedup 1.0000x reference)
//
#include <hip/hip_runtime.h>
#include <math.h>

#define TPB 256

constexpr int Bn    = 131072;
constexpr int F_INn = 30;
constexpr int Hn    = 3;
constexpr float LOG2E = 1.4426950408889634f;

typedef float v2f __attribute__((ext_vector_type(2)));

__global__ __launch_bounds__(TPB)
void gat_ppo_kernel(const float* __restrict__ xg,
                    const float* __restrict__ adjg,
                    const float* __restrict__ Wg,
                    const float* __restrict__ ahg,
                    const float* __restrict__ wog,
                    const float* __restrict__ aog,
                    const float* __restrict__ muWg,
                    const float* __restrict__ mubg,
                    const float* __restrict__ sgWg,
                    const float* __restrict__ sgbg,
                    const float* __restrict__ vWg,
                    const float* __restrict__ vbg,
                    float* __restrict__ outg)
{
    __shared__ float xs[TPB * 15];  // 15360 B -> 8 blocks/CU possible

    const int lb = threadIdx.x;
    const int t  = blockIdx.x * TPB + lb;   // global row index = b*8 + n
    const int n  = lb & 7;                  // node id

    // ---- adj row: 8 consecutive floats per thread, coalesced (issue early) ----
    float adjr[8];
    {
        const float4* a4 = (const float4*)(adjg) + (size_t)t * 2;
        float4 a0 = a4[0], a1 = a4[1];
        adjr[0] = a0.x; adjr[1] = a0.y; adjr[2] = a0.z; adjr[3] = a0.w;
        adjr[4] = a1.x; adjr[5] = a1.y; adjr[6] = a1.z; adjr[7] = a1.w;
    }

    // ---- stage x in two 15KB phases (halves LDS vs one-shot 30KB) ----
    float x[F_INn];
    {
        const float* src = xg + (size_t)blockIdx.x * (TPB * F_INn);
        #pragma unroll
        for (int half = 0; half < 2; ++half) {
            const float2* s2 = (const float2*)(src + half * (TPB * 15));
            float2* d2 = (float2*)xs;
            #pragma unroll
            for (int k = 0; k < 7; ++k)
                d2[lb + k * TPB] = s2[lb + k * TPB];
            if (lb < TPB / 2)
                d2[lb + 7 * TPB] = s2[lb + 7 * TPB];
            __syncthreads();
            if ((lb >> 7) == half) {
                const float2* xr2 = (const float2*)xs + (lb & 127) * 15;
                #pragma unroll
                for (int k = 0; k < 15; ++k) {
                    float2 v = xr2[k];
                    x[2 * k] = v.x; x[2 * k + 1] = v.y;
                }
            }
            __syncthreads();
        }
    }

    // ---- Wh via packed fp32 FMA (v_pk_fma_f32); f1/f2 in log2 domain ----
    const v2f* Wp = (const v2f*)Wg;    // pairs over o
    const v2f* ap = (const v2f*)ahg;
    float wh[Hn][8];
    float f1v[Hn], f2v[Hn];
    #pragma unroll
    for (int h = 0; h < Hn; ++h) {
        v2f acc[4];
        #pragma unroll
        for (int o2 = 0; o2 < 4; ++o2) acc[o2] = (v2f){0.0f, 0.0f};
        #pragma unroll
        for (int f = 0; f < F_INn; ++f) {
            v2f xf = (v2f){x[f], x[f]};
            #pragma unroll
            for (int o2 = 0; o2 < 4; ++o2)
                acc[o2] = __builtin_elementwise_fma(xf, Wp[h * 120 + f * 4 + o2], acc[o2]);
        }
        v2f s1 = (v2f){0.0f, 0.0f}, s2 = (v2f){0.0f, 0.0f};
        #pragma unroll
        for (int o2 = 0; o2 < 4; ++o2) {
            s1 = __builtin_elementwise_fma(acc[o2], ap[h * 8 + o2],     s1);
            s2 = __builtin_elementwise_fma(acc[o2], ap[h * 8 + 4 + o2], s2);
            wh[h][2 * o2]     = acc[o2].x;
            wh[h][2 * o2 + 1] = acc[o2].y;
        }
        f1v[h] = (s1.x + s1.y) * LOG2E;   // log2-domain scores
        f2v[h] = (s2.x + s2.y) * LOG2E;
    }

    // ---- per-head masked softmax (no max-sub, exp2) + packed aggregation ----
    float wh2 = 0.0f;
    #pragma unroll
    for (int h = 0; h < Hn; ++h) {
        float p[8];
        float s = 0.0f;
        #pragma unroll
        for (int m = 0; m < 8; ++m) {
            float f2m = __shfl(f2v[h], m, 8);
            float ev = f1v[h] + f2m;
            ev = (ev > 0.0f) ? ev : 0.2f * ev;            // leaky (log2-scaled)
            float pe = (adjr[m] > 0.0f) ? exp2f(ev) : 0.0f;
            p[m] = pe; s += pe;
        }
        float rs = 1.0f / s;

        v2f hacc[4];
        #pragma unroll
        for (int o2 = 0; o2 < 4; ++o2) hacc[o2] = (v2f){0.0f, 0.0f};
        #pragma unroll
        for (int m = 0; m < 8; ++m) {
            float attm = p[m] * rs;
            v2f av = (v2f){attm, attm};
            float w0 = __shfl(wh[h][0], m, 8);
            float w1 = __shfl(wh[h][1], m, 8);
            float w2 = __shfl(wh[h][2], m, 8);
            float w3 = __shfl(wh[h][3], m, 8);
            float w4 = __shfl(wh[h][4], m, 8);
            float w5 = __shfl(wh[h][5], m, 8);
            float w6 = __shfl(wh[h][6], m, 8);
            float w7 = __shfl(wh[h][7], m, 8);
            hacc[0] = __builtin_elementwise_fma(av, (v2f){w0, w1}, hacc[0]);
            hacc[1] = __builtin_elementwise_fma(av, (v2f){w2, w3}, hacc[1]);
            hacc[2] = __builtin_elementwise_fma(av, (v2f){w4, w5}, hacc[2]);
            hacc[3] = __builtin_elementwise_fma(av, (v2f){w6, w7}, hacc[3]);
        }
        #pragma unroll
        for (int o2 = 0; o2 < 4; ++o2) {
            #pragma unroll
            for (int j = 0; j < 2; ++j) {
                float hv = hacc[o2][j];
                hv = (hv > 0.0f) ? hv : (__expf(hv) - 1.0f);   // elu
                wh2 = fmaf(hv, wog[h * 8 + 2 * o2 + j], wh2);  // h @ W_out
            }
        }
    }

    // ---- second GAT layer on Wh2 (log2-domain scores, no max-sub) ----
    const float a0c = aog[0] * LOG2E, a1c = aog[1] * LOG2E;
    float wh2a[8];
    #pragma unroll
    for (int m = 0; m < 8; ++m) wh2a[m] = __shfl(wh2, m, 8);

    float g1 = a0c * wh2;
    float p2[8];
    float s2s = 0.0f;
    #pragma unroll
    for (int m = 0; m < 8; ++m) {
        float ev = fmaf(a1c, wh2a[m], g1);
        ev = (ev > 0.0f) ? ev : 0.2f * ev;
        float pe = (adjr[m] > 0.0f) ? exp2f(ev) : 0.0f;
        p2[m] = pe; s2s += pe;
    }
    float rs2 = 1.0f / s2s;
    float og = 0.0f;
    #pragma unroll
    for (int m = 0; m < 8; ++m) og = fmaf(p2[m] * rs2, wh2a[m], og);
    float g = (og > 0.0f) ? og : (__expf(og) - 1.0f);     // elu -> g[b][n]

    // ---- MLP heads: mu, sigma (per node j=n), value (per batch) ----
    v2f gp[4];
    #pragma unroll
    for (int m = 0; m < 4; ++m)
        gp[m] = (v2f){__shfl(g, 2 * m, 8), __shfl(g, 2 * m + 1, 8)};

    const v2f* muWp = (const v2f*)muWg;
    const v2f* sgWp = (const v2f*)sgWg;
    const v2f* vWp  = (const v2f*)vWg;
    v2f ma = (v2f){0.0f, 0.0f}, sa = (v2f){0.0f, 0.0f}, va = (v2f){0.0f, 0.0f};
    #pragma unroll
    for (int k = 0; k < 4; ++k) {
        ma = __builtin_elementwise_fma(gp[k], muWp[n * 4 + k], ma);
        sa = __builtin_elementwise_fma(gp[k], sgWp[n * 4 + k], sa);
        va = __builtin_elementwise_fma(gp[k], vWp[k],          va);
    }
    float mu = ma.x + ma.y + mubg[n];
    float sg = sa.x + sa.y + sgbg[n];
    float vv = va.x + va.y + vbg[0];

    mu = 1.0f / (1.0f + __expf(-mu));                               // sigmoid
    sg = fmaxf(sg, 0.0f) + log1pf(__expf(-fabsf(sg))) + 0.001f;     // softplus + 1e-3

    outg[t]          = mu;
    outg[Bn * 8 + t] = sg;
    if (n == 0) outg[Bn * 16 + (t >> 3)] = vv;
}

extern "C" void kernel_launch(void* const* d_in, const int* in_sizes, int n_in,
                              void* d_out, int out_size, void* d_ws, size_t ws_size,
                              hipStream_t stream) {
    const float* xg   = (const float*)d_in[0];
    const float* adjg = (const float*)d_in[1];
    const float* Wg   = (const float*)d_in[2];
    const float* ahg  = (const float*)d_in[3];
    const float* wog  = (const float*)d_in[4];
    const float* aog  = (const float*)d_in[5];
    const float* muW  = (const float*)d_in[6];
    const float* mub  = (const float*)d_in[7];
    const float* sgW  = (const float*)d_in[8];
    const float* sgb  = (const float*)d_in[9];
    const float* vW   = (const float*)d_in[10];
    const float* vb   = (const float*)d_in[11];
    float* outg = (float*)d_out;

    dim3 grid(Bn * 8 / TPB);  // 4096 blocks of 256 threads; 8 lanes per batch
    gat_ppo_kernel<<<grid, TPB, 0, stream>>>(xg, adjg, Wg, ahg, wog, aog,
                                             muW, mub, sgW, sgb, vW, vb, outg);
}

// Round 3
// 61.111 us; speedup vs baseline: 1.7930x; 1.7930x over previous
//
#include <hip/hip_runtime.h>
#include <math.h>

#define TPB 256

constexpr int Bn    = 131072;
constexpr float LOG2E = 1.4426950408889634f;

typedef float v2f __attribute__((ext_vector_type(2)));

__global__ __launch_bounds__(TPB)
void gat_ppo_kernel(const float* __restrict__ xg,
                    const float* __restrict__ adjg,
                    const float* __restrict__ Wg,
                    const float* __restrict__ ahg,
                    const float* __restrict__ wog,
                    const float* __restrict__ aog,
                    const float* __restrict__ muWg,
                    const float* __restrict__ mubg,
                    const float* __restrict__ sgWg,
                    const float* __restrict__ sgbg,
                    const float* __restrict__ vWg,
                    const float* __restrict__ vbg,
                    float* __restrict__ outg)
{
    __shared__ float xs[TPB * 30];  // 30 KB, one-shot staging (round-1 structure)

    const int lb = threadIdx.x;
    const int t  = blockIdx.x * TPB + lb;   // global row index = b*8 + n
    const int n  = lb & 7;                  // node id

    // ---- stage x tile coalesced (float2, single phase, single barrier) ----
    {
        const float2* src = (const float2*)(xg) + (size_t)blockIdx.x * (TPB * 15);
        float2* dst = (float2*)xs;
        #pragma unroll
        for (int k = 0; k < 15; ++k)
            dst[lb + k * TPB] = src[lb + k * TPB];
    }

    // ---- adj row -> 8-bit mask (frees float regs early) ----
    unsigned amask;
    {
        const float4* a4 = (const float4*)(adjg) + (size_t)t * 2;
        float4 a0 = a4[0], a1 = a4[1];
        amask =  (unsigned)(a0.x > 0.0f)
              | ((unsigned)(a0.y > 0.0f) << 1)
              | ((unsigned)(a0.z > 0.0f) << 2)
              | ((unsigned)(a0.w > 0.0f) << 3)
              | ((unsigned)(a1.x > 0.0f) << 4)
              | ((unsigned)(a1.y > 0.0f) << 5)
              | ((unsigned)(a1.z > 0.0f) << 6)
              | ((unsigned)(a1.w > 0.0f) << 7);
    }

    __syncthreads();

    // ---- x row into registers ----
    float x[30];
    {
        const float2* xr = (const float2*)(xs) + lb * 15;
        #pragma unroll
        for (int k = 0; k < 15; ++k) {
            float2 v = xr[k];
            x[2 * k] = v.x; x[2 * k + 1] = v.y;
        }
    }

    // ---- Wh via packed fp32 FMA (v_pk_fma_f32), unpack to scalar wh ----
    const v2f* Wp = (const v2f*)Wg;    // pairs over o
    float wh[3][8];
    float f1v[3], f2v[3];
    #pragma unroll
    for (int h = 0; h < 3; ++h) {
        v2f acc[4];
        #pragma unroll
        for (int o2 = 0; o2 < 4; ++o2) acc[o2] = (v2f){0.0f, 0.0f};
        #pragma unroll
        for (int f = 0; f < 30; ++f) {
            v2f xf = (v2f){x[f], x[f]};
            #pragma unroll
            for (int o2 = 0; o2 < 4; ++o2)
                acc[o2] = __builtin_elementwise_fma(xf, Wp[h * 120 + f * 4 + o2], acc[o2]);
        }
        #pragma unroll
        for (int o2 = 0; o2 < 4; ++o2) {
            wh[h][2 * o2]     = acc[o2].x;
            wh[h][2 * o2 + 1] = acc[o2].y;
        }
        float s1 = 0.0f, s2 = 0.0f;
        #pragma unroll
        for (int o = 0; o < 8; ++o) {
            s1 = fmaf(wh[h][o], ahg[h * 16 + o],     s1);
            s2 = fmaf(wh[h][o], ahg[h * 16 + 8 + o], s2);
        }
        f1v[h] = s1 * LOG2E;   // log2-domain scores (leaky is pos-homogeneous)
        f2v[h] = s2 * LOG2E;
    }

    // ---- per-head masked softmax (no max-pass, exp2) + packed aggregation ----
    float wh2 = 0.0f;
    #pragma unroll
    for (int h = 0; h < 3; ++h) {
        float p[8];
        float s = 0.0f;
        #pragma unroll
        for (int m = 0; m < 8; ++m) {
            float ev = f1v[h] + __shfl(f2v[h], m, 8);
            ev = (ev > 0.0f) ? ev : 0.2f * ev;            // leaky (log2-scaled)
            float pe = ((amask >> m) & 1u) ? exp2f(ev) : 0.0f;
            p[m] = pe; s += pe;
        }
        float rs = 1.0f / s;

        v2f hacc[4];
        #pragma unroll
        for (int o2 = 0; o2 < 4; ++o2) hacc[o2] = (v2f){0.0f, 0.0f};
        #pragma unroll
        for (int m = 0; m < 8; ++m) {
            float attm = p[m] * rs;
            v2f av = (v2f){attm, attm};
            float w0 = __shfl(wh[h][0], m, 8);
            float w1 = __shfl(wh[h][1], m, 8);
            float w2 = __shfl(wh[h][2], m, 8);
            float w3 = __shfl(wh[h][3], m, 8);
            float w4 = __shfl(wh[h][4], m, 8);
            float w5 = __shfl(wh[h][5], m, 8);
            float w6 = __shfl(wh[h][6], m, 8);
            float w7 = __shfl(wh[h][7], m, 8);
            hacc[0] = __builtin_elementwise_fma(av, (v2f){w0, w1}, hacc[0]);
            hacc[1] = __builtin_elementwise_fma(av, (v2f){w2, w3}, hacc[1]);
            hacc[2] = __builtin_elementwise_fma(av, (v2f){w4, w5}, hacc[2]);
            hacc[3] = __builtin_elementwise_fma(av, (v2f){w6, w7}, hacc[3]);
        }
        #pragma unroll
        for (int o2 = 0; o2 < 4; ++o2) {
            #pragma unroll
            for (int j = 0; j < 2; ++j) {
                float hv = hacc[o2][j];
                hv = (hv > 0.0f) ? hv : (__expf(hv) - 1.0f);   // elu
                wh2 = fmaf(hv, wog[h * 8 + 2 * o2 + j], wh2);  // h @ W_out
            }
        }
    }

    // ---- second GAT layer on Wh2 (log2 domain, no max-pass) ----
    const float a0c = aog[0] * LOG2E, a1c = aog[1] * LOG2E;
    float wh2a[8];
    #pragma unroll
    for (int m = 0; m < 8; ++m) wh2a[m] = __shfl(wh2, m, 8);

    float g1 = a0c * wh2;
    float p2[8];
    float s2s = 0.0f;
    #pragma unroll
    for (int m = 0; m < 8; ++m) {
        float ev = fmaf(a1c, wh2a[m], g1);
        ev = (ev > 0.0f) ? ev : 0.2f * ev;
        float pe = ((amask >> m) & 1u) ? exp2f(ev) : 0.0f;
        p2[m] = pe; s2s += pe;
    }
    float rs2 = 1.0f / s2s;
    float og = 0.0f;
    #pragma unroll
    for (int m = 0; m < 8; ++m) og = fmaf(p2[m] * rs2, wh2a[m], og);
    float g = (og > 0.0f) ? og : (__expf(og) - 1.0f);     // elu -> g[b][n]

    // ---- MLP heads: mu, sigma (per node j=n), value (per batch) ----
    float gall[8];
    #pragma unroll
    for (int m = 0; m < 8; ++m) gall[m] = __shfl(g, m, 8);

    float mu = mubg[n];
    float sg = sgbg[n];
    float vv = vbg[0];
    #pragma unroll
    for (int k = 0; k < 8; ++k) {
        mu = fmaf(gall[k], muWg[n * 8 + k], mu);
        sg = fmaf(gall[k], sgWg[n * 8 + k], sg);
        vv = fmaf(gall[k], vWg[k],          vv);
    }
    mu = 1.0f / (1.0f + __expf(-mu));                               // sigmoid
    sg = fmaxf(sg, 0.0f) + log1pf(__expf(-fabsf(sg))) + 0.001f;     // softplus + 1e-3

    outg[t]          = mu;
    outg[Bn * 8 + t] = sg;
    if (n == 0) outg[Bn * 16 + (t >> 3)] = vv;
}

extern "C" void kernel_launch(void* const* d_in, const int* in_sizes, int n_in,
                              void* d_out, int out_size, void* d_ws, size_t ws_size,
                              hipStream_t stream) {
    const float* xg   = (const float*)d_in[0];
    const float* adjg = (const float*)d_in[1];
    const float* Wg   = (const float*)d_in[2];
    const float* ahg  = (const float*)d_in[3];
    const float* wog  = (const float*)d_in[4];
    const float* aog  = (const float*)d_in[5];
    const float* muW  = (const float*)d_in[6];
    const float* mub  = (const float*)d_in[7];
    const float* sgW  = (const float*)d_in[8];
    const float* sgb  = (const float*)d_in[9];
    const float* vW   = (const float*)d_in[10];
    const float* vb   = (const float*)d_in[11];
    float* outg = (float*)d_out;

    dim3 grid(Bn * 8 / TPB);  // 4096 blocks of 256 threads; 8 lanes per batch
    gat_ppo_kernel<<<grid, TPB, 0, stream>>>(xg, adjg, Wg, ahg, wog, aog,
                                             muW, mub, sgW, sgb, vW, vb, outg);
}

// Round 4
// 50.564 us; speedup vs baseline: 2.1670x; 1.2086x over previous
//
#include <hip/hip_runtime.h>
#include <math.h>

#define TPB 256

constexpr int Bn    = 131072;
constexpr float LOG2E = 1.4426950408889634f;

typedef float v2f __attribute__((ext_vector_type(2)));

__global__ __launch_bounds__(TPB)
void gat_ppo_kernel(const float* __restrict__ xg,
                    const float* __restrict__ adjg,
                    const float* __restrict__ Wg,
                    const float* __restrict__ ahg,
                    const float* __restrict__ wog,
                    const float* __restrict__ aog,
                    const float* __restrict__ muWg,
                    const float* __restrict__ mubg,
                    const float* __restrict__ sgWg,
                    const float* __restrict__ sgbg,
                    const float* __restrict__ vWg,
                    const float* __restrict__ vbg,
                    float* __restrict__ outg)
{
    // One 30KB array; each wave owns a 1920-float slice.
    // Slice layout over time: [x staging: 64 rows x 30 floats] then (aliased,
    // after x is in regs) [wh tiles: 8 batches x 100 floats (12-float m-stride)].
    __shared__ float xs[TPB * 30];

    const int lb = threadIdx.x;
    const int w  = lb >> 6;                 // wave id in block
    const int wl = lb & 63;                 // lane in wave
    const int g  = wl >> 3;                 // graph (batch) within wave
    const int n  = lb & 7;                  // node id
    const int t  = blockIdx.x * TPB + lb;   // global row index = b*8 + n

    float* slice = xs + w * (64 * 30);

    // ---- wave-local coalesced staging of x (NO block barrier) ----
    {
        const float2* src = (const float2*)(xg)
                          + (size_t)blockIdx.x * (TPB * 15) + w * (64 * 15);
        float2* dst = (float2*)slice;
        #pragma unroll
        for (int k = 0; k < 15; ++k)
            dst[wl + k * 64] = src[wl + k * 64];
    }

    // ---- adj row -> 8-bit mask ----
    unsigned amask;
    {
        const float4* a4 = (const float4*)(adjg) + (size_t)t * 2;
        float4 a0 = a4[0], a1 = a4[1];
        amask =  (unsigned)(a0.x > 0.0f)
              | ((unsigned)(a0.y > 0.0f) << 1)
              | ((unsigned)(a0.z > 0.0f) << 2)
              | ((unsigned)(a0.w > 0.0f) << 3)
              | ((unsigned)(a1.x > 0.0f) << 4)
              | ((unsigned)(a1.y > 0.0f) << 5)
              | ((unsigned)(a1.z > 0.0f) << 6)
              | ((unsigned)(a1.w > 0.0f) << 7);
    }

    // ---- x row into registers (same wave wrote it; lgkmcnt wait only) ----
    float x[30];
    {
        const float2* xr = (const float2*)slice + wl * 15;
        #pragma unroll
        for (int k = 0; k < 15; ++k) {
            float2 v = xr[k];
            x[2 * k] = v.x; x[2 * k + 1] = v.y;
        }
    }

    // ---- per-head: Wh row (pk-FMA) -> LDS tile -> softmax -> aggregate ----
    float4* wt4 = (float4*)slice;           // aliases dead x staging area
    const v2f* Wp = (const v2f*)Wg;
    float wh2 = 0.0f;

    #pragma unroll
    for (int h = 0; h < 3; ++h) {
        // Wh[n][o] for own row, packed pairs over o
        v2f acc[4];
        #pragma unroll
        for (int o2 = 0; o2 < 4; ++o2) acc[o2] = (v2f){0.0f, 0.0f};
        #pragma unroll
        for (int f = 0; f < 30; ++f) {
            v2f xf = (v2f){x[f], x[f]};
            #pragma unroll
            for (int o2 = 0; o2 < 4; ++o2)
                acc[o2] = __builtin_elementwise_fma(xf, Wp[h * 120 + f * 4 + o2], acc[o2]);
        }

        // f1, f2 scores (log2 domain)
        float s1 = 0.0f, s2 = 0.0f;
        #pragma unroll
        for (int o2 = 0; o2 < 4; ++o2) {
            s1 = fmaf(acc[o2].x, ahg[h * 16 + 2 * o2],     s1);
            s1 = fmaf(acc[o2].y, ahg[h * 16 + 2 * o2 + 1], s1);
            s2 = fmaf(acc[o2].x, ahg[h * 16 + 8 + 2 * o2],     s2);
            s2 = fmaf(acc[o2].y, ahg[h * 16 + 8 + 2 * o2 + 1], s2);
        }
        float f1h = s1 * LOG2E;
        float f2h = s2 * LOG2E;

        // publish own Wh row to the wave-local tile (2 x b128)
        wt4[g * 25 + n * 3]     = (float4){acc[0].x, acc[0].y, acc[1].x, acc[1].y};
        wt4[g * 25 + n * 3 + 1] = (float4){acc[2].x, acc[2].y, acc[3].x, acc[3].y};

        // masked softmax over neighbors (no max pass, exp2)
        float p[8];
        float s = 0.0f;
        #pragma unroll
        for (int m = 0; m < 8; ++m) {
            float ev = f1h + __shfl(f2h, m, 8);
            ev = (ev > 0.0f) ? ev : 0.2f * ev;            // leaky (log2-scaled)
            float pe = ((amask >> m) & 1u) ? __builtin_amdgcn_exp2f(ev) : 0.0f;
            p[m] = pe; s += pe;
        }
        float rs = 1.0f / s;

        // aggregate: read tile rows (broadcast across the graph's 8 lanes)
        v2f hacc[4];
        #pragma unroll
        for (int o2 = 0; o2 < 4; ++o2) hacc[o2] = (v2f){0.0f, 0.0f};
        #pragma unroll
        for (int m = 0; m < 8; ++m) {
            float4 lo = wt4[g * 25 + m * 3];
            float4 hi = wt4[g * 25 + m * 3 + 1];
            float attm = p[m] * rs;
            v2f av = (v2f){attm, attm};
            hacc[0] = __builtin_elementwise_fma(av, (v2f){lo.x, lo.y}, hacc[0]);
            hacc[1] = __builtin_elementwise_fma(av, (v2f){lo.z, lo.w}, hacc[1]);
            hacc[2] = __builtin_elementwise_fma(av, (v2f){hi.x, hi.y}, hacc[2]);
            hacc[3] = __builtin_elementwise_fma(av, (v2f){hi.z, hi.w}, hacc[3]);
        }
        #pragma unroll
        for (int o2 = 0; o2 < 4; ++o2) {
            #pragma unroll
            for (int j = 0; j < 2; ++j) {
                float hv = hacc[o2][j];
                hv = (hv > 0.0f) ? hv : (__expf(hv) - 1.0f);   // elu
                wh2 = fmaf(hv, wog[h * 8 + 2 * o2 + j], wh2);  // h @ W_out
            }
        }
    }

    // ---- second GAT layer on Wh2 (log2 domain, no max pass) ----
    const float a0c = aog[0] * LOG2E, a1c = aog[1] * LOG2E;
    float wh2a[8];
    #pragma unroll
    for (int m = 0; m < 8; ++m) wh2a[m] = __shfl(wh2, m, 8);

    float g1 = a0c * wh2;
    float p2[8];
    float s2s = 0.0f;
    #pragma unroll
    for (int m = 0; m < 8; ++m) {
        float ev = fmaf(a1c, wh2a[m], g1);
        ev = (ev > 0.0f) ? ev : 0.2f * ev;
        float pe = ((amask >> m) & 1u) ? __builtin_amdgcn_exp2f(ev) : 0.0f;
        p2[m] = pe; s2s += pe;
    }
    float rs2 = 1.0f / s2s;
    float og = 0.0f;
    #pragma unroll
    for (int m = 0; m < 8; ++m) og = fmaf(p2[m] * rs2, wh2a[m], og);
    float g2v = (og > 0.0f) ? og : (__expf(og) - 1.0f);   // elu -> g[b][n]

    // ---- MLP heads: mu, sigma (per node), value (per batch) ----
    float gall[8];
    #pragma unroll
    for (int m = 0; m < 8; ++m) gall[m] = __shfl(g2v, m, 8);

    float mu = mubg[n];
    float sg = sgbg[n];
    float vv = vbg[0];
    #pragma unroll
    for (int k = 0; k < 8; ++k) {
        mu = fmaf(gall[k], muWg[n * 8 + k], mu);
        sg = fmaf(gall[k], sgWg[n * 8 + k], sg);
        vv = fmaf(gall[k], vWg[k],          vv);
    }
    mu = 1.0f / (1.0f + __expf(-mu));                               // sigmoid
    sg = fmaxf(sg, 0.0f) + log1pf(__expf(-fabsf(sg))) + 0.001f;     // softplus + 1e-3

    outg[t]          = mu;
    outg[Bn * 8 + t] = sg;
    if (n == 0) outg[Bn * 16 + (t >> 3)] = vv;
}

extern "C" void kernel_launch(void* const* d_in, const int* in_sizes, int n_in,
                              void* d_out, int out_size, void* d_ws, size_t ws_size,
                              hipStream_t stream) {
    const float* xg   = (const float*)d_in[0];
    const float* adjg = (const float*)d_in[1];
    const float* Wg   = (const float*)d_in[2];
    const float* ahg  = (const float*)d_in[3];
    const float* wog  = (const float*)d_in[4];
    const float* aog  = (const float*)d_in[5];
    const float* muW  = (const float*)d_in[6];
    const float* mub  = (const float*)d_in[7];
    const float* sgW  = (const float*)d_in[8];
    const float* sgb  = (const float*)d_in[9];
    const float* vW   = (const float*)d_in[10];
    const float* vb   = (const float*)d_in[11];
    float* outg = (float*)d_out;

    dim3 grid(Bn * 8 / TPB);  // 4096 blocks of 256 threads; 8 lanes per graph
    gat_ppo_kernel<<<grid, TPB, 0, stream>>>(xg, adjg, Wg, ahg, wog, aog,
                                             muW, mub, sgW, sgb, vW, vb, outg);
}

// Round 5
// 50.368 us; speedup vs baseline: 2.1754x; 1.0039x over previous
//
#include <hip/hip_runtime.h>
#include <math.h>

#define TPB 256

constexpr int Bn    = 131072;
constexpr float LOG2E = 1.4426950408889634f;

typedef float v2f __attribute__((ext_vector_type(2)));

__global__ __launch_bounds__(TPB)
void gat_ppo_kernel(const float* __restrict__ xg,
                    const float* __restrict__ adjg,
                    const float* __restrict__ Wg,
                    const float* __restrict__ ahg,
                    const float* __restrict__ wog,
                    const float* __restrict__ aog,
                    const float* __restrict__ muWg,
                    const float* __restrict__ mubg,
                    const float* __restrict__ sgWg,
                    const float* __restrict__ sgbg,
                    const float* __restrict__ vWg,
                    const float* __restrict__ vbg,
                    float* __restrict__ outg)
{
    // Only the per-wave Wh tile lives in LDS now: 4 waves x 200 float4 = 12.8 KB
    // -> 8 blocks/CU possible (100% occupancy cap).
    __shared__ float4 tile[4 * 200];

    const int lb = threadIdx.x;
    const int w  = lb >> 6;                 // wave id in block
    const int g  = (lb & 63) >> 3;          // graph within wave
    const int n  = lb & 7;                  // node id
    const int t  = blockIdx.x * TPB + lb;   // global row index = b*8 + n

    float4* wt4 = tile + w * 200;

    // ---- adj row -> 8-bit mask ----
    unsigned amask;
    {
        const float4* a4 = (const float4*)(adjg) + (size_t)t * 2;
        float4 a0 = a4[0], a1 = a4[1];
        amask =  (unsigned)(a0.x > 0.0f)
              | ((unsigned)(a0.y > 0.0f) << 1)
              | ((unsigned)(a0.z > 0.0f) << 2)
              | ((unsigned)(a0.w > 0.0f) << 3)
              | ((unsigned)(a1.x > 0.0f) << 4)
              | ((unsigned)(a1.y > 0.0f) << 5)
              | ((unsigned)(a1.z > 0.0f) << 6)
              | ((unsigned)(a1.w > 0.0f) << 7);
    }

    // ---- x row: direct per-lane loads (wave spans 7.7KB contiguous; L1-served) ----
    float x[30];
    {
        const float2* xr = (const float2*)(xg + (size_t)t * 30);
        #pragma unroll
        for (int k = 0; k < 15; ++k) {
            float2 v = xr[k];
            x[2 * k] = v.x; x[2 * k + 1] = v.y;
        }
    }

    // ---- per-head: Wh row (pk-FMA) -> LDS tile -> softmax -> aggregate ----
    const v2f* Wp = (const v2f*)Wg;
    float wh2 = 0.0f;

    #pragma unroll
    for (int h = 0; h < 3; ++h) {
        v2f acc[4];
        #pragma unroll
        for (int o2 = 0; o2 < 4; ++o2) acc[o2] = (v2f){0.0f, 0.0f};
        #pragma unroll
        for (int f = 0; f < 30; ++f) {
            v2f xf = (v2f){x[f], x[f]};
            #pragma unroll
            for (int o2 = 0; o2 < 4; ++o2)
                acc[o2] = __builtin_elementwise_fma(xf, Wp[h * 120 + f * 4 + o2], acc[o2]);
        }

        // f1, f2 scores (log2 domain)
        float s1 = 0.0f, s2 = 0.0f;
        #pragma unroll
        for (int o2 = 0; o2 < 4; ++o2) {
            s1 = fmaf(acc[o2].x, ahg[h * 16 + 2 * o2],     s1);
            s1 = fmaf(acc[o2].y, ahg[h * 16 + 2 * o2 + 1], s1);
            s2 = fmaf(acc[o2].x, ahg[h * 16 + 8 + 2 * o2],     s2);
            s2 = fmaf(acc[o2].y, ahg[h * 16 + 8 + 2 * o2 + 1], s2);
        }
        float f1h = s1 * LOG2E;
        float f2h = s2 * LOG2E;

        // publish own Wh row to the wave-local tile (2 x b128)
        wt4[g * 25 + n * 3]     = (float4){acc[0].x, acc[0].y, acc[1].x, acc[1].y};
        wt4[g * 25 + n * 3 + 1] = (float4){acc[2].x, acc[2].y, acc[3].x, acc[3].y};

        // masked softmax weights, unnormalized (no max pass, exp2)
        float p[8];
        float s = 0.0f;
        #pragma unroll
        for (int m = 0; m < 8; ++m) {
            float ev = f1h + __shfl(f2h, m, 8);
            ev = fmaxf(ev, 0.2f * ev);                    // leaky (log2-scaled)
            float pe = ((amask >> m) & 1u) ? __builtin_amdgcn_exp2f(ev) : 0.0f;
            p[m] = pe; s += pe;
        }

        // aggregate unnormalized; divide once at the end
        v2f hacc[4];
        #pragma unroll
        for (int o2 = 0; o2 < 4; ++o2) hacc[o2] = (v2f){0.0f, 0.0f};
        #pragma unroll
        for (int m = 0; m < 8; ++m) {
            float4 lo = wt4[g * 25 + m * 3];
            float4 hi = wt4[g * 25 + m * 3 + 1];
            v2f av = (v2f){p[m], p[m]};
            hacc[0] = __builtin_elementwise_fma(av, (v2f){lo.x, lo.y}, hacc[0]);
            hacc[1] = __builtin_elementwise_fma(av, (v2f){lo.z, lo.w}, hacc[1]);
            hacc[2] = __builtin_elementwise_fma(av, (v2f){hi.x, hi.y}, hacc[2]);
            hacc[3] = __builtin_elementwise_fma(av, (v2f){hi.z, hi.w}, hacc[3]);
        }
        float rs = 1.0f / s;
        #pragma unroll
        for (int o2 = 0; o2 < 4; ++o2) {
            #pragma unroll
            for (int j = 0; j < 2; ++j) {
                float hv = hacc[o2][j] * rs;
                hv = (hv > 0.0f) ? hv : (__expf(hv) - 1.0f);   // elu
                wh2 = fmaf(hv, wog[h * 8 + 2 * o2 + j], wh2);  // h @ W_out
            }
        }
    }

    // ---- second GAT layer on Wh2 (log2 domain, no max pass, deferred norm) ----
    const float a0c = aog[0] * LOG2E, a1c = aog[1] * LOG2E;
    float wh2a[8];
    #pragma unroll
    for (int m = 0; m < 8; ++m) wh2a[m] = __shfl(wh2, m, 8);

    float g1 = a0c * wh2;
    float s2s = 0.0f;
    float og = 0.0f;
    #pragma unroll
    for (int m = 0; m < 8; ++m) {
        float ev = fmaf(a1c, wh2a[m], g1);
        ev = fmaxf(ev, 0.2f * ev);
        float pe = ((amask >> m) & 1u) ? __builtin_amdgcn_exp2f(ev) : 0.0f;
        s2s += pe;
        og = fmaf(pe, wh2a[m], og);
    }
    og /= s2s;
    float g2v = (og > 0.0f) ? og : (__expf(og) - 1.0f);   // elu -> g[b][n]

    // ---- MLP heads: mu, sigma (per node), value (per batch) ----
    v2f gp[4];
    #pragma unroll
    for (int m = 0; m < 4; ++m)
        gp[m] = (v2f){__shfl(g2v, 2 * m, 8), __shfl(g2v, 2 * m + 1, 8)};

    const v2f* muWp = (const v2f*)muWg;
    const v2f* sgWp = (const v2f*)sgWg;
    const v2f* vWp  = (const v2f*)vWg;
    v2f ma = (v2f){0.0f, 0.0f}, sa = (v2f){0.0f, 0.0f}, va = (v2f){0.0f, 0.0f};
    #pragma unroll
    for (int k = 0; k < 4; ++k) {
        ma = __builtin_elementwise_fma(gp[k], muWp[n * 4 + k], ma);
        sa = __builtin_elementwise_fma(gp[k], sgWp[n * 4 + k], sa);
        va = __builtin_elementwise_fma(gp[k], vWp[k],          va);
    }
    float mu = ma.x + ma.y + mubg[n];
    float sg = sa.x + sa.y + sgbg[n];
    float vv = va.x + va.y + vbg[0];

    mu = 1.0f / (1.0f + __expf(-mu));                               // sigmoid
    sg = fmaxf(sg, 0.0f) + log1pf(__expf(-fabsf(sg))) + 0.001f;     // softplus + 1e-3

    outg[t]          = mu;
    outg[Bn * 8 + t] = sg;
    if (n == 0) outg[Bn * 16 + (t >> 3)] = vv;
}

extern "C" void kernel_launch(void* const* d_in, const int* in_sizes, int n_in,
                              void* d_out, int out_size, void* d_ws, size_t ws_size,
                              hipStream_t stream) {
    const float* xg   = (const float*)d_in[0];
    const float* adjg = (const float*)d_in[1];
    const float* Wg   = (const float*)d_in[2];
    const float* ahg  = (const float*)d_in[3];
    const float* wog  = (const float*)d_in[4];
    const float* aog  = (const float*)d_in[5];
    const float* muW  = (const float*)d_in[6];
    const float* mub  = (const float*)d_in[7];
    const float* sgW  = (const float*)d_in[8];
    const float* sgb  = (const float*)d_in[9];
    const float* vW   = (const float*)d_in[10];
    const float* vb   = (const float*)d_in[11];
    float* outg = (float*)d_out;

    dim3 grid(Bn * 8 / TPB);  // 4096 blocks of 256 threads; 8 lanes per graph
    gat_ppo_kernel<<<grid, TPB, 0, stream>>>(xg, adjg, Wg, ahg, wog, aog,
                                             muW, mub, sgW, sgb, vW, vb, outg);
}